// Round 8
// baseline (134.031 us; speedup 1.0000x reference)
//
#include <hip/hip_runtime.h>

// Problem: B=4, C=256, C4=64, N=4096, f32 in/out.
//   Q = Wqk@x; V = Wv@x + b; E = Q^T Q / 8; A = softmax_rows(E); out = V @ A
// Fused: out[c,m] = sum_n (V[c,n]/Z[n]) * exp(E[n,m]),  Z[n] = sum_m exp(E[n,m])
// exp via v_exp_f32 (__builtin_amdgcn_exp2f): Qt scaled by sqrt(log2e/8).
// z pass: no shift (2^12 folded exactly into u_kernel). av pass: SHIFT2=12
// keeps P in normal-f16 range. P stays IN REGISTERS (E-MFMA D-layout ==
// PV B-frag layout for mfma_f32_16x16x16f16). Both z and av use explicit
// even/odd double-buffered prefetch (named regs) to hide L2 latency.

#define CC 256
#define C4C 64
#define NBATCH 4
#define NN 4096
#define QSCALE 0.42466089f   // sqrt(log2(e)/8)
#define SHIFT2 12.0f

typedef _Float16 f16;
typedef _Float16 half2v __attribute__((ext_vector_type(2)));
typedef _Float16 half4 __attribute__((ext_vector_type(4)));
typedef _Float16 half8 __attribute__((ext_vector_type(8)));
typedef __fp16 fp16x2 __attribute__((ext_vector_type(2)));
typedef float floatx4 __attribute__((ext_vector_type(4)));

static __device__ __forceinline__ half2v pkrtz(float a, float b) {
  fp16x2 r = __builtin_amdgcn_cvt_pkrtz(a, b);
  return __builtin_bit_cast(half2v, r);
}

// ---------------- QV: Q/V projections via MFMA ----------------
// grid (128, 4) block 256 (4 waves). Block tile: 128 oc x 32 n, K=C=256.
#define XT_PITCH 264
__global__ __launch_bounds__(256) void qv_kernel(
    const float* __restrict__ x, const float* __restrict__ Wqk,
    const float* __restrict__ Wv, const float* __restrict__ bv,
    f16* __restrict__ Qt, float* __restrict__ V)
{
  __shared__ __align__(16) f16 xt[32][XT_PITCH];
  const int b = blockIdx.y;
  const int n0 = blockIdx.x * 32;
  const int tid = threadIdx.x;

  {
    const int nq = tid & 7;
    const int cb = tid >> 3;
    const int c = cb * 8;
    const float* xp = x + (size_t)b * CC * NN + n0 + nq * 4;
    float4 r[8];
#pragma unroll
    for (int j = 0; j < 8; ++j)
      r[j] = *(const float4*)(xp + (size_t)(c + j) * NN);
#pragma unroll
    for (int s = 0; s < 4; ++s) {
      half8 h;
#pragma unroll
      for (int j = 0; j < 8; ++j) h[j] = (f16)(((const float*)&r[j])[s]);
      *(half8*)(&xt[nq * 4 + s][c]) = h;
    }
  }

  const int w = tid >> 6, l = tid & 63, lr = l & 15, lg = l >> 4;
  const float* Wsrc = (w < 2) ? Wqk : Wv;
  const int ocb = (w & 1) * 32;
  half8 af[2][8];
#pragma unroll
  for (int t = 0; t < 2; ++t) {
    const float* wp = Wsrc + (size_t)(ocb + t * 16 + lr) * CC + 8 * lg;
#pragma unroll
    for (int kk = 0; kk < 8; ++kk) {
      float4 wa = *(const float4*)(wp + kk * 32);
      float4 wb = *(const float4*)(wp + kk * 32 + 4);
      half8 h;
      h[0] = (f16)wa.x; h[1] = (f16)wa.y; h[2] = (f16)wa.z; h[3] = (f16)wa.w;
      h[4] = (f16)wb.x; h[5] = (f16)wb.y; h[6] = (f16)wb.z; h[7] = (f16)wb.w;
      af[t][kk] = h;
    }
  }

  __syncthreads();

  floatx4 acc[2][2] = {{{0.f,0.f,0.f,0.f},{0.f,0.f,0.f,0.f}},
                       {{0.f,0.f,0.f,0.f},{0.f,0.f,0.f,0.f}}};
#pragma unroll
  for (int nt = 0; nt < 2; ++nt) {
#pragma unroll
    for (int kk = 0; kk < 8; ++kk) {
      half8 bf = *(const half8*)(&xt[nt * 16 + lr][kk * 32 + 8 * lg]);
      acc[0][nt] = __builtin_amdgcn_mfma_f32_16x16x32_f16(af[0][kk], bf, acc[0][nt], 0, 0, 0);
      acc[1][nt] = __builtin_amdgcn_mfma_f32_16x16x32_f16(af[1][kk], bf, acc[1][nt], 0, 0, 0);
    }
  }

  if (w < 2) {
#pragma unroll
    for (int t = 0; t < 2; ++t)
#pragma unroll
      for (int nt = 0; nt < 2; ++nt) {
        int n = n0 + nt * 16 + lr;
        int oc = w * 32 + t * 16 + 4 * lg;
        union { f16 h[4]; unsigned long long u; } q4;
#pragma unroll
        for (int i = 0; i < 4; ++i) q4.h[i] = (f16)(acc[t][nt][i] * QSCALE);
        *(unsigned long long*)(Qt + ((size_t)(b * NN) + n) * 64 + oc) = q4.u;
      }
  } else {
#pragma unroll
    for (int t = 0; t < 2; ++t)
#pragma unroll
      for (int nt = 0; nt < 2; ++nt) {
        int n = n0 + nt * 16 + lr;
        int oc = (w - 2) * 32 + t * 16 + 4 * lg;
#pragma unroll
        for (int i = 0; i < 4; ++i)
          V[((size_t)(b * C4C) + oc + i) * NN + n] = acc[t][nt][i] + bv[oc + i];
      }
  }
}

// ---------------- Z pass (double-buffered prefetch) ----------------
// Zp[mc][b][n0..n0+32) = sum over m-chunk of exp2(dot) (NO shift; 2^12 in u_kernel).
// grid 4096 (1D, XCD-swizzled) block 256 (4 waves). Disjoint 128-m wave strips.
#define LOADB(MROW, B0, B1)                                                \
  { const f16* bp_ = Qb + ((size_t)((MROW) + lr)) * 64 + 8 * lg;           \
    B0 = *(const half8*)(bp_); B1 = *(const half8*)(bp_ + 32); }

#define Z_STEP(B0, B1)                                                    \
  { _Pragma("unroll")                                                     \
    for (int t = 0; t < 2; ++t) {                                         \
      floatx4 d = {0.f, 0.f, 0.f, 0.f};                                   \
      d = __builtin_amdgcn_mfma_f32_16x16x32_f16(a[t][0], B0, d, 0, 0, 0);\
      d = __builtin_amdgcn_mfma_f32_16x16x32_f16(a[t][1], B1, d, 0, 0, 0);\
      _Pragma("unroll")                                                   \
      for (int i = 0; i < 4; ++i) rs[t][i] += __builtin_amdgcn_exp2f(d[i]); } }

__global__ __launch_bounds__(256, 8) void z_kernel(
    const f16* __restrict__ Qt, float* __restrict__ Zp)
{
  __shared__ float zl[4][32];
  const int bx = blockIdx.x;
  const int xcd = bx & 7, slot = bx >> 3;       // slot 0..511
  const int b = xcd >> 1;                        // 2 XCDs per batch
  const int wu = ((xcd & 1) << 9) | slot;        // 0..1023 per batch
  const int n0 = (wu >> 3) * 32;
  const int mc = wu & 7;
  const int tid = threadIdx.x;
  const int w = tid >> 6, l = tid & 63, lr = l & 15, lg = l >> 4;
  const f16* Qb = Qt + (size_t)b * NN * 64;

  half8 a[2][2];
#pragma unroll
  for (int t = 0; t < 2; ++t) {
    const f16* ap = Qb + ((size_t)(n0 + 16 * t + lr)) * 64 + 8 * lg;
    a[t][0] = *(const half8*)(ap);
    a[t][1] = *(const half8*)(ap + 32);
  }

  float rs[2][4] = {{0.f,0.f,0.f,0.f},{0.f,0.f,0.f,0.f}};
  const int mbeg = mc * 512 + w * 128;
  half8 bA0, bA1, bB0, bB1;
  LOADB(mbeg, bA0, bA1);
#pragma unroll
  for (int mt = 0; mt < 8; mt += 2) {
    LOADB(mbeg + (mt + 1) * 16, bB0, bB1);
    Z_STEP(bA0, bA1);
    if (mt + 2 < 8) LOADB(mbeg + (mt + 2) * 16, bA0, bA1);
    Z_STEP(bB0, bB1);
  }
#pragma unroll
  for (int t = 0; t < 2; ++t)
#pragma unroll
    for (int i = 0; i < 4; ++i) {
      float v = rs[t][i];
      v += __shfl_xor(v, 1); v += __shfl_xor(v, 2);
      v += __shfl_xor(v, 4); v += __shfl_xor(v, 8);
      rs[t][i] = v;
    }
  if (lr == 0) {
#pragma unroll
    for (int t = 0; t < 2; ++t)
#pragma unroll
      for (int i = 0; i < 4; ++i)
        zl[w][16 * t + 4 * lg + i] = rs[t][i];
  }
  __syncthreads();
  if (tid < 32) {   // fixed-order cross-wave sum: deterministic
    float s = zl[0][tid] + zl[1][tid] + zl[2][tid] + zl[3][tid];
    Zp[(size_t)mc * NBATCH * NN + b * NN + n0 + tid] = s;
  }
}

// ---------------- Z reduce: Z[i] = sum_k Zp[k][i] (fixed order) ----------------
__global__ __launch_bounds__(256) void zr_kernel(
    const float* __restrict__ Zp, float* __restrict__ Z)
{
  int i = blockIdx.x * 256 + threadIdx.x;   // 4*4096 = 16384
  float s = 0.f;
#pragma unroll
  for (int k = 0; k < 8; ++k) s += Zp[(size_t)k * NBATCH * NN + i];
  Z[i] = s;
}

// ---------------- U: blocked U4[b][n/16][c][16] = V * 2^12 / Zraw (fp16) -------
__global__ __launch_bounds__(256) void u_kernel(
    const float* __restrict__ V, const float* __restrict__ Z,
    f16* __restrict__ U4)
{
  size_t t = (size_t)blockIdx.x * 256 + threadIdx.x;  // 128K threads
  size_t e = t * 8;
  int b = (int)(e >> 18);
  int c = (int)((e >> 12) & 63);
  int n = (int)(e & (NN - 1));
  const float* vp = V + (size_t)b * C4C * NN + (size_t)c * NN + n;
  float4 v0 = *(const float4*)(vp);
  float4 v1 = *(const float4*)(vp + 4);
  const float* zp = Z + b * NN + n;
  float4 z0 = *(const float4*)(zp);
  float4 z1 = *(const float4*)(zp + 4);
  half2v h0 = pkrtz(v0.x * 4096.0f / z0.x, v0.y * 4096.0f / z0.y);
  half2v h1 = pkrtz(v0.z * 4096.0f / z0.z, v0.w * 4096.0f / z0.w);
  half2v h2 = pkrtz(v1.x * 4096.0f / z1.x, v1.y * 4096.0f / z1.y);
  half2v h3 = pkrtz(v1.z * 4096.0f / z1.z, v1.w * 4096.0f / z1.w);
  half8 h = {h0[0], h0[1], h1[0], h1[1], h2[0], h2[1], h3[0], h3[1]};
  *(half8*)(U4 + (size_t)b * (C4C * NN) + (size_t)(n >> 4) * 1024 + c * 16 + (n & 15)) = h;
}

// ---------------- PV pass: prefetched, register-resident P --------------------
// grid 1024 (1D, XCD-swizzled) block 512 (8 waves) -> 2 blocks/CU (VGPR~100).
// Block: 32 m-cols x n-half (2048). Per iter (128 n): wave w owns ns=...+16w.
//   E: A = Qt rows, B = hoisted m-frags -> D = P[n(4lg+i)][m(lr)]
//   exp2 -> pkrtz f16 in-register == B-frag of mfma_f32_16x16x16f16; PV K=16.
// Even/odd double-buffered prefetch of A-frags + ua.
// End: fixed-order 8-wave LDS reduce, then atomicAdd (2 commutative
// contributors per output from the nh halves -> bitwise deterministic).
#define LOADA(NS, A0, A1)                                                  \
  { const f16* ap_ = Qb + ((size_t)((NS) + lr)) * 64 + 8 * lg;             \
    A0 = *(const half8*)(ap_); A1 = *(const half8*)(ap_ + 32); }

#define LOADU(NB, UA)                                                      \
  { const f16* up_ = Ub + (size_t)(NB) * 1024 + 4 * lg;                    \
    _Pragma("unroll")                                                      \
    for (int cs = 0; cs < 4; ++cs)                                         \
      UA[cs] = *(const half4*)(up_ + (16 * cs + lr) * 16); }

#define AV_STEP(A0, A1, UA)                                                \
  { _Pragma("unroll")                                                      \
    for (int t = 0; t < 2; ++t) {                                          \
      floatx4 d = {0.f, 0.f, 0.f, 0.f};                                    \
      d = __builtin_amdgcn_mfma_f32_16x16x32_f16(A0, bq[t][0], d, 0, 0, 0);\
      d = __builtin_amdgcn_mfma_f32_16x16x32_f16(A1, bq[t][1], d, 0, 0, 0);\
      half2v p01 = pkrtz(__builtin_amdgcn_exp2f(d[0] - SHIFT2),            \
                         __builtin_amdgcn_exp2f(d[1] - SHIFT2));           \
      half2v p23 = pkrtz(__builtin_amdgcn_exp2f(d[2] - SHIFT2),            \
                         __builtin_amdgcn_exp2f(d[3] - SHIFT2));           \
      half4 bt = {p01[0], p01[1], p23[0], p23[1]};                         \
      _Pragma("unroll")                                                    \
      for (int cs = 0; cs < 4; ++cs)                                       \
        o[cs][t] = __builtin_amdgcn_mfma_f32_16x16x16f16(UA[cs], bt, o[cs][t], 0, 0, 0); } }

__global__ __launch_bounds__(512, 4) void av_kernel(
    const f16* __restrict__ Qt, const f16* __restrict__ U4,
    float* __restrict__ Out)
{
  __shared__ float red[8][2][16][17];  // ~17.4 KB

  const int bx = blockIdx.x;
  const int xcd = bx & 7, slot = bx >> 3;          // slot 0..127
  const int b = xcd >> 1;                          // 2 XCDs per batch
  const int wu = ((xcd & 1) << 7) | slot;          // 0..255 per batch
  const int m0 = (wu >> 1) * 32;                   // 128 m-tiles
  const int nh = wu & 1;                           // n-half
  const int nbase = nh * 2048;
  const int tid = threadIdx.x;
  const int w = tid >> 6;                          // 0..7
  const int l = tid & 63;
  const int lr = l & 15, lg = l >> 4;

  const f16* Qb = Qt + (size_t)b * NN * 64;
  const f16* Ub = U4 + (size_t)b * (C4C * NN);

  // hoisted E B-frags for the 32-m tile
  half8 bq[2][2];
#pragma unroll
  for (int t = 0; t < 2; ++t) {
    const f16* bp = Qb + ((size_t)(m0 + 16 * t + lr)) * 64 + 8 * lg;
    bq[t][0] = *(const half8*)(bp);
    bq[t][1] = *(const half8*)(bp + 32);
  }

  floatx4 o[4][2];
#pragma unroll
  for (int cs = 0; cs < 4; ++cs)
#pragma unroll
    for (int t = 0; t < 2; ++t) o[cs][t] = (floatx4){0.f, 0.f, 0.f, 0.f};

  const int nb0 = (nbase >> 4);                    // U4 n-block base
  half8 aA0, aA1, aB0, aB1;
  half4 uA[4], uB[4];
  LOADA(nbase + 16 * w, aA0, aA1);
  LOADU(nb0 + w, uA);
#pragma unroll
  for (int it = 0; it < 16; it += 2) {
    LOADA(nbase + (it + 1) * 128 + 16 * w, aB0, aB1);
    LOADU(nb0 + (it + 1) * 8 + w, uB);
    AV_STEP(aA0, aA1, uA);
    if (it + 2 < 16) {
      LOADA(nbase + (it + 2) * 128 + 16 * w, aA0, aA1);
      LOADU(nb0 + (it + 2) * 8 + w, uA);
    }
    AV_STEP(aB0, aB1, uB);
  }

  // ---- 8-wave reduction, fixed order, then 2-contributor atomicAdd ----
#pragma unroll 1
  for (int cs = 0; cs < 4; ++cs) {
    __syncthreads();
#pragma unroll
    for (int t = 0; t < 2; ++t)
#pragma unroll
      for (int i = 0; i < 4; ++i)
        red[w][t][4 * lg + i][lr] = o[cs][t][i];
    __syncthreads();
    const int t = tid >> 8;              // 0..1
    const int r = (tid >> 4) & 15;       // 0..15
    const int col = tid & 15;            // 0..15
    float s = 0.f;
#pragma unroll
    for (int ww = 0; ww < 8; ++ww) s += red[ww][t][r][col];
    atomicAdd(&Out[((size_t)b * C4C + cs * 16 + r) * NN + m0 + t * 16 + col], s);
  }
}

// ---------------- launch ----------------
// ws layout (~8.45 MB, Zp aliased over U4 region — dead before U4 is written):
//   Qt  f16 [4][4096][64]      2 MiB    @ 0
//   V   f32 [4][64][4096]      4 MiB    @ 2 MiB
//   Z   f32 [4][4096]          64 KiB   @ 6 MiB
//   U4  f16 [4][256][64][16]   2 MiB    @ 6 MiB + 64 KiB
//   Zp  f32 [8][4][4096]       512 KiB  @ 6 MiB + 64 KiB (aliases U4)
extern "C" void kernel_launch(void* const* d_in, const int* in_sizes, int n_in,
                              void* d_out, int out_size, void* d_ws, size_t ws_size,
                              hipStream_t stream)
{
  const float* x   = (const float*)d_in[0];
  const float* Wqk = (const float*)d_in[1];
  const float* Wv  = (const float*)d_in[2];
  const float* bv  = (const float*)d_in[3];
  float* out = (float*)d_out;

  char* ws = (char*)d_ws;
  f16*   Qt = (f16*)(ws);
  float* V  = (float*)(ws + (2u << 20));
  float* Z  = (float*)(ws + (6u << 20));
  f16*   U4 = (f16*)(ws + (6u << 20) + (64u << 10));
  float* Zp = (float*)(ws + (6u << 20) + (64u << 10));  // alias: dead before U4

  hipMemsetAsync(out, 0, (size_t)out_size * sizeof(float), stream);

  qv_kernel<<<dim3(128, 4), 256, 0, stream>>>(x, Wqk, Wv, bv, Qt, V);
  z_kernel<<<dim3(4096), 256, 0, stream>>>(Qt, Zp);
  zr_kernel<<<dim3(64), 256, 0, stream>>>(Zp, Z);
  u_kernel<<<dim3(512), 256, 0, stream>>>(V, Z, U4);
  av_kernel<<<dim3(1024), 512, 0, stream>>>(Qt, U4, out);
}

// Round 9
// 107.123 us; speedup vs baseline: 1.2512x; 1.2512x over previous
//
#include <hip/hip_runtime.h>

// Problem: B=4, C=256, C4=64, N=4096, f32 in/out.
//   Q = Wqk@x; V = Wv@x + b; E = Q^T Q / 8; A = softmax_rows(E); out = V @ A
// Fused: out[c,m] = sum_n (V[c,n]/Z[n]) * exp(E[n,m]),  Z[n] = sum_m exp(E[n,m])
// exp via v_exp_f32 (__builtin_amdgcn_exp2f): Qt scaled by sqrt(log2e/8).
// z pass: no shift (2^12 folded exactly into u_kernel). av pass: SHIFT2=12
// keeps P in normal-f16 range. P stays IN REGISTERS (E-MFMA D-layout ==
// PV B-frag layout for mfma_f32_16x16x16f16).
// R9: z keeps reg prefetch but WITHOUT the (,8) VGPR clamp (R8 spilled:
// WRITE_SIZE 111 MB of scratch). av reverted to the R7-measured-56us version.

#define CC 256
#define C4C 64
#define NBATCH 4
#define NN 4096
#define QSCALE 0.42466089f   // sqrt(log2(e)/8)
#define SHIFT2 12.0f

typedef _Float16 f16;
typedef _Float16 half2v __attribute__((ext_vector_type(2)));
typedef _Float16 half4 __attribute__((ext_vector_type(4)));
typedef _Float16 half8 __attribute__((ext_vector_type(8)));
typedef __fp16 fp16x2 __attribute__((ext_vector_type(2)));
typedef float floatx4 __attribute__((ext_vector_type(4)));

static __device__ __forceinline__ half2v pkrtz(float a, float b) {
  fp16x2 r = __builtin_amdgcn_cvt_pkrtz(a, b);
  return __builtin_bit_cast(half2v, r);
}

// ---------------- QV: Q/V projections via MFMA ----------------
// grid (128, 4) block 256 (4 waves). Block tile: 128 oc x 32 n, K=C=256.
#define XT_PITCH 264
__global__ __launch_bounds__(256) void qv_kernel(
    const float* __restrict__ x, const float* __restrict__ Wqk,
    const float* __restrict__ Wv, const float* __restrict__ bv,
    f16* __restrict__ Qt, float* __restrict__ V)
{
  __shared__ __align__(16) f16 xt[32][XT_PITCH];
  const int b = blockIdx.y;
  const int n0 = blockIdx.x * 32;
  const int tid = threadIdx.x;

  {
    const int nq = tid & 7;
    const int cb = tid >> 3;
    const int c = cb * 8;
    const float* xp = x + (size_t)b * CC * NN + n0 + nq * 4;
    float4 r[8];
#pragma unroll
    for (int j = 0; j < 8; ++j)
      r[j] = *(const float4*)(xp + (size_t)(c + j) * NN);
#pragma unroll
    for (int s = 0; s < 4; ++s) {
      half8 h;
#pragma unroll
      for (int j = 0; j < 8; ++j) h[j] = (f16)(((const float*)&r[j])[s]);
      *(half8*)(&xt[nq * 4 + s][c]) = h;
    }
  }

  const int w = tid >> 6, l = tid & 63, lr = l & 15, lg = l >> 4;
  const float* Wsrc = (w < 2) ? Wqk : Wv;
  const int ocb = (w & 1) * 32;
  half8 af[2][8];
#pragma unroll
  for (int t = 0; t < 2; ++t) {
    const float* wp = Wsrc + (size_t)(ocb + t * 16 + lr) * CC + 8 * lg;
#pragma unroll
    for (int kk = 0; kk < 8; ++kk) {
      float4 wa = *(const float4*)(wp + kk * 32);
      float4 wb = *(const float4*)(wp + kk * 32 + 4);
      half8 h;
      h[0] = (f16)wa.x; h[1] = (f16)wa.y; h[2] = (f16)wa.z; h[3] = (f16)wa.w;
      h[4] = (f16)wb.x; h[5] = (f16)wb.y; h[6] = (f16)wb.z; h[7] = (f16)wb.w;
      af[t][kk] = h;
    }
  }

  __syncthreads();

  floatx4 acc[2][2] = {{{0.f,0.f,0.f,0.f},{0.f,0.f,0.f,0.f}},
                       {{0.f,0.f,0.f,0.f},{0.f,0.f,0.f,0.f}}};
#pragma unroll
  for (int nt = 0; nt < 2; ++nt) {
#pragma unroll
    for (int kk = 0; kk < 8; ++kk) {
      half8 bf = *(const half8*)(&xt[nt * 16 + lr][kk * 32 + 8 * lg]);
      acc[0][nt] = __builtin_amdgcn_mfma_f32_16x16x32_f16(af[0][kk], bf, acc[0][nt], 0, 0, 0);
      acc[1][nt] = __builtin_amdgcn_mfma_f32_16x16x32_f16(af[1][kk], bf, acc[1][nt], 0, 0, 0);
    }
  }

  if (w < 2) {
#pragma unroll
    for (int t = 0; t < 2; ++t)
#pragma unroll
      for (int nt = 0; nt < 2; ++nt) {
        int n = n0 + nt * 16 + lr;
        int oc = w * 32 + t * 16 + 4 * lg;
        union { f16 h[4]; unsigned long long u; } q4;
#pragma unroll
        for (int i = 0; i < 4; ++i) q4.h[i] = (f16)(acc[t][nt][i] * QSCALE);
        *(unsigned long long*)(Qt + ((size_t)(b * NN) + n) * 64 + oc) = q4.u;
      }
  } else {
#pragma unroll
    for (int t = 0; t < 2; ++t)
#pragma unroll
      for (int nt = 0; nt < 2; ++nt) {
        int n = n0 + nt * 16 + lr;
        int oc = (w - 2) * 32 + t * 16 + 4 * lg;
#pragma unroll
        for (int i = 0; i < 4; ++i)
          V[((size_t)(b * C4C) + oc + i) * NN + n] = acc[t][nt][i] + bv[oc + i];
      }
  }
}

// ---------------- Z pass (double-buffered prefetch, NO VGPR clamp) ----------
// Zp[mc][b][n0..n0+32) = sum over m-chunk of exp2(dot) (NO shift; 2^12 in u_kernel).
// grid 4096 (1D, XCD-swizzled) block 256 (4 waves). Disjoint 128-m wave strips.
#define LOADB(MROW, B0, B1)                                                \
  { const f16* bp_ = Qb + ((size_t)((MROW) + lr)) * 64 + 8 * lg;           \
    B0 = *(const half8*)(bp_); B1 = *(const half8*)(bp_ + 32); }

#define Z_STEP(B0, B1)                                                    \
  { _Pragma("unroll")                                                     \
    for (int t = 0; t < 2; ++t) {                                         \
      floatx4 d = {0.f, 0.f, 0.f, 0.f};                                   \
      d = __builtin_amdgcn_mfma_f32_16x16x32_f16(a[t][0], B0, d, 0, 0, 0);\
      d = __builtin_amdgcn_mfma_f32_16x16x32_f16(a[t][1], B1, d, 0, 0, 0);\
      _Pragma("unroll")                                                   \
      for (int i = 0; i < 4; ++i) rs[t][i] += __builtin_amdgcn_exp2f(d[i]); } }

__global__ __launch_bounds__(256) void z_kernel(
    const f16* __restrict__ Qt, float* __restrict__ Zp)
{
  __shared__ float zl[4][32];
  const int bx = blockIdx.x;
  const int xcd = bx & 7, slot = bx >> 3;       // slot 0..511
  const int b = xcd >> 1;                        // 2 XCDs per batch
  const int wu = ((xcd & 1) << 9) | slot;        // 0..1023 per batch
  const int n0 = (wu >> 3) * 32;
  const int mc = wu & 7;
  const int tid = threadIdx.x;
  const int w = tid >> 6, l = tid & 63, lr = l & 15, lg = l >> 4;
  const f16* Qb = Qt + (size_t)b * NN * 64;

  half8 a[2][2];
#pragma unroll
  for (int t = 0; t < 2; ++t) {
    const f16* ap = Qb + ((size_t)(n0 + 16 * t + lr)) * 64 + 8 * lg;
    a[t][0] = *(const half8*)(ap);
    a[t][1] = *(const half8*)(ap + 32);
  }

  float rs[2][4] = {{0.f,0.f,0.f,0.f},{0.f,0.f,0.f,0.f}};
  const int mbeg = mc * 512 + w * 128;
  half8 bA0, bA1, bB0, bB1;
  LOADB(mbeg, bA0, bA1);
#pragma unroll
  for (int mt = 0; mt < 8; mt += 2) {
    LOADB(mbeg + (mt + 1) * 16, bB0, bB1);
    Z_STEP(bA0, bA1);
    if (mt + 2 < 8) LOADB(mbeg + (mt + 2) * 16, bA0, bA1);
    Z_STEP(bB0, bB1);
  }
#pragma unroll
  for (int t = 0; t < 2; ++t)
#pragma unroll
    for (int i = 0; i < 4; ++i) {
      float v = rs[t][i];
      v += __shfl_xor(v, 1); v += __shfl_xor(v, 2);
      v += __shfl_xor(v, 4); v += __shfl_xor(v, 8);
      rs[t][i] = v;
    }
  if (lr == 0) {
#pragma unroll
    for (int t = 0; t < 2; ++t)
#pragma unroll
      for (int i = 0; i < 4; ++i)
        zl[w][16 * t + 4 * lg + i] = rs[t][i];
  }
  __syncthreads();
  if (tid < 32) {   // fixed-order cross-wave sum: deterministic
    float s = zl[0][tid] + zl[1][tid] + zl[2][tid] + zl[3][tid];
    Zp[(size_t)mc * NBATCH * NN + b * NN + n0 + tid] = s;
  }
}

// ---------------- Z reduce: Z[i] = sum_k Zp[k][i] (fixed order) ----------------
__global__ __launch_bounds__(256) void zr_kernel(
    const float* __restrict__ Zp, float* __restrict__ Z)
{
  int i = blockIdx.x * 256 + threadIdx.x;   // 4*4096 = 16384
  float s = 0.f;
#pragma unroll
  for (int k = 0; k < 8; ++k) s += Zp[(size_t)k * NBATCH * NN + i];
  Z[i] = s;
}

// ---------------- U: blocked U4[b][n/16][c][16] = V * 2^12 / Zraw (fp16) -------
__global__ __launch_bounds__(256) void u_kernel(
    const float* __restrict__ V, const float* __restrict__ Z,
    f16* __restrict__ U4)
{
  size_t t = (size_t)blockIdx.x * 256 + threadIdx.x;  // 128K threads
  size_t e = t * 8;
  int b = (int)(e >> 18);
  int c = (int)((e >> 12) & 63);
  int n = (int)(e & (NN - 1));
  const float* vp = V + (size_t)b * C4C * NN + (size_t)c * NN + n;
  float4 v0 = *(const float4*)(vp);
  float4 v1 = *(const float4*)(vp + 4);
  const float* zp = Z + b * NN + n;
  float4 z0 = *(const float4*)(zp);
  float4 z1 = *(const float4*)(zp + 4);
  half2v h0 = pkrtz(v0.x * 4096.0f / z0.x, v0.y * 4096.0f / z0.y);
  half2v h1 = pkrtz(v0.z * 4096.0f / z0.z, v0.w * 4096.0f / z0.w);
  half2v h2 = pkrtz(v1.x * 4096.0f / z1.x, v1.y * 4096.0f / z1.y);
  half2v h3 = pkrtz(v1.z * 4096.0f / z1.z, v1.w * 4096.0f / z1.w);
  half8 h = {h0[0], h0[1], h1[0], h1[1], h2[0], h2[1], h3[0], h3[1]};
  *(half8*)(U4 + (size_t)b * (C4C * NN) + (size_t)(n >> 4) * 1024 + c * 16 + (n & 15)) = h;
}

// ---------------- PV pass (R7 version, measured 56us) -------------------------
// grid 256 (1D, XCD-swizzled) block 1024 (16 waves). Block: 64 m, all n.
// Per iter (256 n): wave w owns ns = it*256+16w.
//   E: A = Qt rows, B = hoisted m-frags -> D = P[n(4lg+i)][m(lr)]
//   exp2 -> pkrtz f16 in-register == B-frag of mfma_f32_16x16x16f16; PV K=16.
// End: fixed-order 16-wave LDS reduction (deterministic), direct stores.
__global__ __launch_bounds__(1024, 4) void av_kernel(
    const f16* __restrict__ Qt, const f16* __restrict__ U4,
    float* __restrict__ Out)
{
  __shared__ float red[16][4][16][17];  // ~70 KB, pitch 17

  const int bx = blockIdx.x;
  const int xcd = bx & 7, slot = bx >> 3;          // slot 0..31
  const int b = xcd >> 1;                          // 2 XCDs per batch
  const int m0 = (((xcd & 1) << 5) | slot) * 64;   // 64 m-tiles per batch
  const int tid = threadIdx.x;
  const int w = tid >> 6;                          // 0..15
  const int l = tid & 63;
  const int lr = l & 15, lg = l >> 4;

  const f16* Qb = Qt + (size_t)b * NN * 64;
  const f16* Ub = U4 + (size_t)b * (C4C * NN);

  // hoisted E B-frags for the 64-m tile
  half8 bq[4][2];
#pragma unroll
  for (int t = 0; t < 4; ++t) {
    const f16* bp = Qb + ((size_t)(m0 + 16 * t + lr)) * 64 + 8 * lg;
    bq[t][0] = *(const half8*)(bp);
    bq[t][1] = *(const half8*)(bp + 32);
  }

  floatx4 o[4][4];
#pragma unroll
  for (int cs = 0; cs < 4; ++cs)
#pragma unroll
    for (int t = 0; t < 4; ++t) o[cs][t] = (floatx4){0.f, 0.f, 0.f, 0.f};

#pragma unroll 1
  for (int it = 0; it < 16; ++it) {
    const int ns = it * 256 + 16 * w;              // this wave's n-strip
    const f16* ap = Qb + ((size_t)(ns + lr)) * 64 + 8 * lg;
    half8 a0 = *(const half8*)(ap);
    half8 a1 = *(const half8*)(ap + 32);
    half4 ua[4];
    const f16* up = Ub + (size_t)(it * 16 + w) * 1024 + 4 * lg;
#pragma unroll
    for (int cs = 0; cs < 4; ++cs)
      ua[cs] = *(const half4*)(up + (16 * cs + lr) * 16);

#pragma unroll
    for (int t = 0; t < 4; ++t) {
      floatx4 d = {0.f, 0.f, 0.f, 0.f};
      d = __builtin_amdgcn_mfma_f32_16x16x32_f16(a0, bq[t][0], d, 0, 0, 0);
      d = __builtin_amdgcn_mfma_f32_16x16x32_f16(a1, bq[t][1], d, 0, 0, 0);
      half2v p01 = pkrtz(__builtin_amdgcn_exp2f(d[0] - SHIFT2),
                         __builtin_amdgcn_exp2f(d[1] - SHIFT2));
      half2v p23 = pkrtz(__builtin_amdgcn_exp2f(d[2] - SHIFT2),
                         __builtin_amdgcn_exp2f(d[3] - SHIFT2));
      half4 bt = {p01[0], p01[1], p23[0], p23[1]};
#pragma unroll
      for (int cs = 0; cs < 4; ++cs)
        o[cs][t] = __builtin_amdgcn_mfma_f32_16x16x16f16(ua[cs], bt, o[cs][t], 0, 0, 0);
    }
  }

  // ---- 16-wave reduction, fixed order: deterministic, no atomics ----
#pragma unroll 1
  for (int cs = 0; cs < 4; ++cs) {
    __syncthreads();
#pragma unroll
    for (int t = 0; t < 4; ++t)
#pragma unroll
      for (int i = 0; i < 4; ++i)
        red[w][t][4 * lg + i][lr] = o[cs][t][i];
    __syncthreads();
    const int t = tid >> 8;              // 0..3
    const int r = (tid >> 4) & 15;       // 0..15
    const int col = tid & 15;            // 0..15
    float s = 0.f;
#pragma unroll
    for (int ww = 0; ww < 16; ++ww) s += red[ww][t][r][col];
    Out[((size_t)b * C4C + cs * 16 + r) * NN + m0 + t * 16 + col] = s;
  }
}

// ---------------- launch ----------------
// ws layout (~8.45 MB, Zp aliased over U4 region — dead before U4 is written):
//   Qt  f16 [4][4096][64]      2 MiB    @ 0
//   V   f32 [4][64][4096]      4 MiB    @ 2 MiB
//   Z   f32 [4][4096]          64 KiB   @ 6 MiB
//   U4  f16 [4][256][64][16]   2 MiB    @ 6 MiB + 64 KiB
//   Zp  f32 [8][4][4096]       512 KiB  @ 6 MiB + 64 KiB (aliases U4)
extern "C" void kernel_launch(void* const* d_in, const int* in_sizes, int n_in,
                              void* d_out, int out_size, void* d_ws, size_t ws_size,
                              hipStream_t stream)
{
  const float* x   = (const float*)d_in[0];
  const float* Wqk = (const float*)d_in[1];
  const float* Wv  = (const float*)d_in[2];
  const float* bv  = (const float*)d_in[3];
  float* out = (float*)d_out;

  char* ws = (char*)d_ws;
  f16*   Qt = (f16*)(ws);
  float* V  = (float*)(ws + (2u << 20));
  float* Z  = (float*)(ws + (6u << 20));
  f16*   U4 = (f16*)(ws + (6u << 20) + (64u << 10));
  float* Zp = (float*)(ws + (6u << 20) + (64u << 10));  // alias: dead before U4

  qv_kernel<<<dim3(128, 4), 256, 0, stream>>>(x, Wqk, Wv, bv, Qt, V);
  z_kernel<<<dim3(4096), 256, 0, stream>>>(Qt, Zp);
  zr_kernel<<<dim3(64), 256, 0, stream>>>(Zp, Z);
  u_kernel<<<dim3(512), 256, 0, stream>>>(V, Z, U4);
  av_kernel<<<dim3(256), 1024, 0, stream>>>(Qt, U4, out);
}

// Round 10
// 102.624 us; speedup vs baseline: 1.3060x; 1.0438x over previous
//
#include <hip/hip_runtime.h>

// Problem: B=4, C=256, C4=64, N=4096, f32 in/out.
//   Q = Wqk@x; V = Wv@x + b; E = Q^T Q / 8; A = softmax_rows(E); out = V @ A
// Fused: out[c,m] = sum_n (V[c,n]/Z[n]) * exp(E[n,m]),  Z[n] = sum_m exp(E[n,m])
// exp via v_exp_f32: Qt scaled by sqrt(log2e/8). z: no shift (2^12 folded into
// u_kernel). av: SHIFT2=12 keeps P normal-f16. P stays IN REGISTERS (E-MFMA
// D-layout == PV B-frag of mfma_f32_16x16x16f16).
// R10: z preloads the ENTIRE m-strip (8 B-frag pairs, ~16 loads in flight);
// av reshaped to 768 thr (12 waves = 3/SIMD, reg cap 170) so a rotating
// even/odd prefetch of (a,ua) fits WITHOUT spilling (R8 lesson: 1024-thr
// blocks cap total regs at 128 = exactly acc+working set, no headroom).

#define CC 256
#define C4C 64
#define NBATCH 4
#define NN 4096
#define QSCALE 0.42466089f   // sqrt(log2(e)/8)
#define SHIFT2 12.0f

typedef _Float16 f16;
typedef _Float16 half2v __attribute__((ext_vector_type(2)));
typedef _Float16 half4 __attribute__((ext_vector_type(4)));
typedef _Float16 half8 __attribute__((ext_vector_type(8)));
typedef __fp16 fp16x2 __attribute__((ext_vector_type(2)));
typedef float floatx4 __attribute__((ext_vector_type(4)));

static __device__ __forceinline__ half2v pkrtz(float a, float b) {
  fp16x2 r = __builtin_amdgcn_cvt_pkrtz(a, b);
  return __builtin_bit_cast(half2v, r);
}

// ---------------- QV: Q/V projections via MFMA ----------------
// grid (128, 4) block 256 (4 waves). Block tile: 128 oc x 32 n, K=C=256.
#define XT_PITCH 264
__global__ __launch_bounds__(256) void qv_kernel(
    const float* __restrict__ x, const float* __restrict__ Wqk,
    const float* __restrict__ Wv, const float* __restrict__ bv,
    f16* __restrict__ Qt, float* __restrict__ V)
{
  __shared__ __align__(16) f16 xt[32][XT_PITCH];
  const int b = blockIdx.y;
  const int n0 = blockIdx.x * 32;
  const int tid = threadIdx.x;

  {
    const int nq = tid & 7;
    const int cb = tid >> 3;
    const int c = cb * 8;
    const float* xp = x + (size_t)b * CC * NN + n0 + nq * 4;
    float4 r[8];
#pragma unroll
    for (int j = 0; j < 8; ++j)
      r[j] = *(const float4*)(xp + (size_t)(c + j) * NN);
#pragma unroll
    for (int s = 0; s < 4; ++s) {
      half8 h;
#pragma unroll
      for (int j = 0; j < 8; ++j) h[j] = (f16)(((const float*)&r[j])[s]);
      *(half8*)(&xt[nq * 4 + s][c]) = h;
    }
  }

  const int w = tid >> 6, l = tid & 63, lr = l & 15, lg = l >> 4;
  const float* Wsrc = (w < 2) ? Wqk : Wv;
  const int ocb = (w & 1) * 32;
  half8 af[2][8];
#pragma unroll
  for (int t = 0; t < 2; ++t) {
    const float* wp = Wsrc + (size_t)(ocb + t * 16 + lr) * CC + 8 * lg;
#pragma unroll
    for (int kk = 0; kk < 8; ++kk) {
      float4 wa = *(const float4*)(wp + kk * 32);
      float4 wb = *(const float4*)(wp + kk * 32 + 4);
      half8 h;
      h[0] = (f16)wa.x; h[1] = (f16)wa.y; h[2] = (f16)wa.z; h[3] = (f16)wa.w;
      h[4] = (f16)wb.x; h[5] = (f16)wb.y; h[6] = (f16)wb.z; h[7] = (f16)wb.w;
      af[t][kk] = h;
    }
  }

  __syncthreads();

  floatx4 acc[2][2] = {{{0.f,0.f,0.f,0.f},{0.f,0.f,0.f,0.f}},
                       {{0.f,0.f,0.f,0.f},{0.f,0.f,0.f,0.f}}};
#pragma unroll
  for (int nt = 0; nt < 2; ++nt) {
#pragma unroll
    for (int kk = 0; kk < 8; ++kk) {
      half8 bf = *(const half8*)(&xt[nt * 16 + lr][kk * 32 + 8 * lg]);
      acc[0][nt] = __builtin_amdgcn_mfma_f32_16x16x32_f16(af[0][kk], bf, acc[0][nt], 0, 0, 0);
      acc[1][nt] = __builtin_amdgcn_mfma_f32_16x16x32_f16(af[1][kk], bf, acc[1][nt], 0, 0, 0);
    }
  }

  if (w < 2) {
#pragma unroll
    for (int t = 0; t < 2; ++t)
#pragma unroll
      for (int nt = 0; nt < 2; ++nt) {
        int n = n0 + nt * 16 + lr;
        int oc = w * 32 + t * 16 + 4 * lg;
        union { f16 h[4]; unsigned long long u; } q4;
#pragma unroll
        for (int i = 0; i < 4; ++i) q4.h[i] = (f16)(acc[t][nt][i] * QSCALE);
        *(unsigned long long*)(Qt + ((size_t)(b * NN) + n) * 64 + oc) = q4.u;
      }
  } else {
#pragma unroll
    for (int t = 0; t < 2; ++t)
#pragma unroll
      for (int nt = 0; nt < 2; ++nt) {
        int n = n0 + nt * 16 + lr;
        int oc = (w - 2) * 32 + t * 16 + 4 * lg;
#pragma unroll
        for (int i = 0; i < 4; ++i)
          V[((size_t)(b * C4C) + oc + i) * NN + n] = acc[t][nt][i] + bv[oc + i];
      }
  }
}

// ---------------- Z pass (FULL-STRIP preload: 8 B-frag pairs in flight) ------
// Zp[mc][b][n0..n0+32) = sum over m-chunk of exp2(dot) (NO shift; 2^12 in u_kernel).
// grid 4096 (1D, XCD-swizzled) block 256 (4 waves). Disjoint 128-m wave strips.
__global__ __launch_bounds__(256) void z_kernel(
    const f16* __restrict__ Qt, float* __restrict__ Zp)
{
  __shared__ float zl[4][32];
  const int bx = blockIdx.x;
  const int xcd = bx & 7, slot = bx >> 3;       // slot 0..511
  const int b = xcd >> 1;                        // 2 XCDs per batch
  const int wu = ((xcd & 1) << 9) | slot;        // 0..1023 per batch
  const int n0 = (wu >> 3) * 32;
  const int mc = wu & 7;
  const int tid = threadIdx.x;
  const int w = tid >> 6, l = tid & 63, lr = l & 15, lg = l >> 4;
  const f16* Qb = Qt + (size_t)b * NN * 64;

  half8 a[2][2];
#pragma unroll
  for (int t = 0; t < 2; ++t) {
    const f16* ap = Qb + ((size_t)(n0 + 16 * t + lr)) * 64 + 8 * lg;
    a[t][0] = *(const half8*)(ap);
    a[t][1] = *(const half8*)(ap + 32);
  }

  const int mbeg = mc * 512 + w * 128;
  // preload the whole 128-m strip: 8 x (2 half8) = 64 VGPR, 16 loads in flight
  half8 bb[8][2];
#pragma unroll
  for (int mt = 0; mt < 8; ++mt) {
    const f16* bp = Qb + ((size_t)(mbeg + mt * 16 + lr)) * 64 + 8 * lg;
    bb[mt][0] = *(const half8*)(bp);
    bb[mt][1] = *(const half8*)(bp + 32);
  }

  float rs[2][4] = {{0.f,0.f,0.f,0.f},{0.f,0.f,0.f,0.f}};
#pragma unroll
  for (int mt = 0; mt < 8; ++mt) {
#pragma unroll
    for (int t = 0; t < 2; ++t) {
      floatx4 d = {0.f, 0.f, 0.f, 0.f};
      d = __builtin_amdgcn_mfma_f32_16x16x32_f16(a[t][0], bb[mt][0], d, 0, 0, 0);
      d = __builtin_amdgcn_mfma_f32_16x16x32_f16(a[t][1], bb[mt][1], d, 0, 0, 0);
#pragma unroll
      for (int i = 0; i < 4; ++i) rs[t][i] += __builtin_amdgcn_exp2f(d[i]);
    }
  }
#pragma unroll
  for (int t = 0; t < 2; ++t)
#pragma unroll
    for (int i = 0; i < 4; ++i) {
      float v = rs[t][i];
      v += __shfl_xor(v, 1); v += __shfl_xor(v, 2);
      v += __shfl_xor(v, 4); v += __shfl_xor(v, 8);
      rs[t][i] = v;
    }
  if (lr == 0) {
#pragma unroll
    for (int t = 0; t < 2; ++t)
#pragma unroll
      for (int i = 0; i < 4; ++i)
        zl[w][16 * t + 4 * lg + i] = rs[t][i];
  }
  __syncthreads();
  if (tid < 32) {   // fixed-order cross-wave sum: deterministic
    float s = zl[0][tid] + zl[1][tid] + zl[2][tid] + zl[3][tid];
    Zp[(size_t)mc * NBATCH * NN + b * NN + n0 + tid] = s;
  }
}

// ---------------- Z reduce: Z[i] = sum_k Zp[k][i] (fixed order) ----------------
__global__ __launch_bounds__(256) void zr_kernel(
    const float* __restrict__ Zp, float* __restrict__ Z)
{
  int i = blockIdx.x * 256 + threadIdx.x;   // 4*4096 = 16384
  float s = 0.f;
#pragma unroll
  for (int k = 0; k < 8; ++k) s += Zp[(size_t)k * NBATCH * NN + i];
  Z[i] = s;
}

// ---------------- U: blocked U4[b][n/16][c][16] = V * 2^12 / Zraw (fp16) -------
__global__ __launch_bounds__(256) void u_kernel(
    const float* __restrict__ V, const float* __restrict__ Z,
    f16* __restrict__ U4)
{
  size_t t = (size_t)blockIdx.x * 256 + threadIdx.x;  // 128K threads
  size_t e = t * 8;
  int b = (int)(e >> 18);
  int c = (int)((e >> 12) & 63);
  int n = (int)(e & (NN - 1));
  const float* vp = V + (size_t)b * C4C * NN + (size_t)c * NN + n;
  float4 v0 = *(const float4*)(vp);
  float4 v1 = *(const float4*)(vp + 4);
  const float* zp = Z + b * NN + n;
  float4 z0 = *(const float4*)(zp);
  float4 z1 = *(const float4*)(zp + 4);
  half2v h0 = pkrtz(v0.x * 4096.0f / z0.x, v0.y * 4096.0f / z0.y);
  half2v h1 = pkrtz(v0.z * 4096.0f / z0.z, v0.w * 4096.0f / z0.w);
  half2v h2 = pkrtz(v1.x * 4096.0f / z1.x, v1.y * 4096.0f / z1.y);
  half2v h3 = pkrtz(v1.z * 4096.0f / z1.z, v1.w * 4096.0f / z1.w);
  half8 h = {h0[0], h0[1], h1[0], h1[1], h2[0], h2[1], h3[0], h3[1]};
  *(half8*)(U4 + (size_t)b * (C4C * NN) + (size_t)(n >> 4) * 1024 + c * 16 + (n & 15)) = h;
}

// ---------------- PV pass: 12 waves, rotating prefetch, register P -----------
// grid 256 (1D, XCD-swizzled) block 768 (12 waves = 3/SIMD, reg cap 170).
// Block: 64 m-cols, all 4096 n (256 strips of 16). Wave w owns strips
// s = w, w+12, ... (ragged: 21-22 each; wave-uniform guard). Rotating
// even/odd prefetch of (A-frags, ua) hides L2 latency under MFMA+exp2.
// End: fixed-order 12-wave LDS reduction (deterministic), direct stores.
#define LOADA(NS, A0, A1)                                                  \
  { const f16* ap_ = Qb + ((size_t)((NS) + lr)) * 64 + 8 * lg;             \
    A0 = *(const half8*)(ap_); A1 = *(const half8*)(ap_ + 32); }

#define LOADU(NB, UA)                                                      \
  { const f16* up_ = Ub + (size_t)(NB) * 1024 + 4 * lg;                    \
    _Pragma("unroll")                                                      \
    for (int cs = 0; cs < 4; ++cs)                                         \
      UA[cs] = *(const half4*)(up_ + (16 * cs + lr) * 16); }

#define AV_STEP(A0, A1, UA)                                                \
  { _Pragma("unroll")                                                      \
    for (int t = 0; t < 4; ++t) {                                          \
      floatx4 d = {0.f, 0.f, 0.f, 0.f};                                    \
      d = __builtin_amdgcn_mfma_f32_16x16x32_f16(A0, bq[t][0], d, 0, 0, 0);\
      d = __builtin_amdgcn_mfma_f32_16x16x32_f16(A1, bq[t][1], d, 0, 0, 0);\
      half2v p01 = pkrtz(__builtin_amdgcn_exp2f(d[0] - SHIFT2),            \
                         __builtin_amdgcn_exp2f(d[1] - SHIFT2));           \
      half2v p23 = pkrtz(__builtin_amdgcn_exp2f(d[2] - SHIFT2),            \
                         __builtin_amdgcn_exp2f(d[3] - SHIFT2));           \
      half4 bt = {p01[0], p01[1], p23[0], p23[1]};                         \
      _Pragma("unroll")                                                    \
      for (int cs = 0; cs < 4; ++cs)                                       \
        o[cs][t] = __builtin_amdgcn_mfma_f32_16x16x16f16(UA[cs], bt, o[cs][t], 0, 0, 0); } }

__global__ __launch_bounds__(768, 3) void av_kernel(
    const f16* __restrict__ Qt, const f16* __restrict__ U4,
    float* __restrict__ Out)
{
  __shared__ float red[12][4][16][17];  // ~52 KB, pitch 17

  const int bx = blockIdx.x;
  const int xcd = bx & 7, slot = bx >> 3;          // slot 0..31
  const int b = xcd >> 1;                          // 2 XCDs per batch
  const int m0 = (((xcd & 1) << 5) | slot) * 64;   // 64 m-tiles per batch
  const int tid = threadIdx.x;
  const int w = tid >> 6;                          // 0..11
  const int l = tid & 63;
  const int lr = l & 15, lg = l >> 4;

  const f16* Qb = Qt + (size_t)b * NN * 64;
  const f16* Ub = U4 + (size_t)b * (C4C * NN);

  // hoisted E B-frags for the 64-m tile (block-uniform values, L2-hot)
  half8 bq[4][2];
#pragma unroll
  for (int t = 0; t < 4; ++t) {
    const f16* bp = Qb + ((size_t)(m0 + 16 * t + lr)) * 64 + 8 * lg;
    bq[t][0] = *(const half8*)(bp);
    bq[t][1] = *(const half8*)(bp + 32);
  }

  floatx4 o[4][4];
#pragma unroll
  for (int cs = 0; cs < 4; ++cs)
#pragma unroll
    for (int t = 0; t < 4; ++t) o[cs][t] = (floatx4){0.f, 0.f, 0.f, 0.f};

  // strip loop: s = w, w+12, ... < 256; 22 fixed iterations, rotating buffers
  int s = w;
  half8 aA0, aA1, aB0, aB1;
  half4 uA[4], uB[4];
  LOADA(s * 16, aA0, aA1);
  LOADU(s, uA);
#pragma unroll 1
  for (int k = 0; k < 22; k += 2) {
    {
      int sn = s + 12;
      int sl = (sn < 256) ? sn : 0;
      LOADA(sl * 16, aB0, aB1);
      LOADU(sl, uB);
      if (s < 256) AV_STEP(aA0, aA1, uA);
      s = sn;
    }
    {
      int sn = s + 12;
      int sl = (sn < 256) ? sn : 0;
      LOADA(sl * 16, aA0, aA1);
      LOADU(sl, uA);
      if (s < 256) AV_STEP(aB0, aB1, uB);
      s = sn;
    }
  }

  // ---- 12-wave reduction, fixed order: deterministic, no atomics ----
#pragma unroll 1
  for (int cs = 0; cs < 4; ++cs) {
    __syncthreads();
#pragma unroll
    for (int t = 0; t < 4; ++t)
#pragma unroll
      for (int i = 0; i < 4; ++i)
        red[w][t][4 * lg + i][lr] = o[cs][t][i];
    __syncthreads();
    for (int idx = tid; idx < 1024; idx += 768) {
      int t = idx >> 8;                // 0..3
      int r = (idx >> 4) & 15;         // 0..15
      int col = idx & 15;              // 0..15
      float ssum = 0.f;
#pragma unroll
      for (int ww = 0; ww < 12; ++ww) ssum += red[ww][t][r][col];
      Out[((size_t)b * C4C + cs * 16 + r) * NN + m0 + t * 16 + col] = ssum;
    }
  }
}

// ---------------- launch ----------------
// ws layout (~8.45 MB, Zp aliased over U4 region — dead before U4 is written):
//   Qt  f16 [4][4096][64]      2 MiB    @ 0
//   V   f32 [4][64][4096]      4 MiB    @ 2 MiB
//   Z   f32 [4][4096]          64 KiB   @ 6 MiB
//   U4  f16 [4][256][64][16]   2 MiB    @ 6 MiB + 64 KiB
//   Zp  f32 [8][4][4096]       512 KiB  @ 6 MiB + 64 KiB (aliases U4)
extern "C" void kernel_launch(void* const* d_in, const int* in_sizes, int n_in,
                              void* d_out, int out_size, void* d_ws, size_t ws_size,
                              hipStream_t stream)
{
  const float* x   = (const float*)d_in[0];
  const float* Wqk = (const float*)d_in[1];
  const float* Wv  = (const float*)d_in[2];
  const float* bv  = (const float*)d_in[3];
  float* out = (float*)d_out;

  char* ws = (char*)d_ws;
  f16*   Qt = (f16*)(ws);
  float* V  = (float*)(ws + (2u << 20));
  float* Z  = (float*)(ws + (6u << 20));
  f16*   U4 = (f16*)(ws + (6u << 20) + (64u << 10));
  float* Zp = (float*)(ws + (6u << 20) + (64u << 10));  // alias: dead before U4

  qv_kernel<<<dim3(128, 4), 256, 0, stream>>>(x, Wqk, Wv, bv, Qt, V);
  z_kernel<<<dim3(4096), 256, 0, stream>>>(Qt, Zp);
  zr_kernel<<<dim3(64), 256, 0, stream>>>(Zp, Z);
  u_kernel<<<dim3(512), 256, 0, stream>>>(V, Z, U4);
  av_kernel<<<dim3(256), 768, 0, stream>>>(Qt, U4, out);
}